// Round 10
// baseline (201.754 us; speedup 1.0000x reference)
//
#include <hip/hip_runtime.h>

typedef __attribute__((ext_vector_type(4))) float f32x4;
typedef __attribute__((ext_vector_type(16))) float f32x16;
typedef __attribute__((ext_vector_type(8))) __bf16 bf16x8;
typedef __attribute__((ext_vector_type(8))) unsigned short ushortx8;
typedef __attribute__((ext_vector_type(4))) unsigned short ushortx4;
typedef unsigned short u16;
typedef unsigned int u32;

#define AS1 __attribute__((address_space(1)))
#define AS3 __attribute__((address_space(3)))

__device__ __forceinline__ void gld_lds16(const void* g, void* s) {
  __builtin_amdgcn_global_load_lds((AS1 void*)g, (AS3 void*)s, 16, 0, 0);
}

__device__ __forceinline__ u16 f2bf(float f) {
  unsigned int u = __float_as_uint(f);
  unsigned int r = (u + 0x7FFFu + ((u >> 16) & 1u)) >> 16;
  return (u16)r;
}

// 0.125 * log2(e): folded into Q columns of W_qkv/b_qkv so QK^T scores are log2-domain
#define QSCALE 0.1803368801111244f

// ---------------- fused prep: cvt x->bf16 | transpose Wqkv | transpose Wout | bias ----
__global__ __launch_bounds__(256) void prep_fused(
    const float* __restrict__ x, u16* __restrict__ xb,
    const float* __restrict__ bqkv, float* __restrict__ bq2,
    const float* __restrict__ Wqkv, u16* __restrict__ wqkvt,
    const float* __restrict__ Wout, u16* __restrict__ woutt) {
  const int gid = blockIdx.x, tid = threadIdx.x;
  if (gid < 2048) {
    const int i = (gid * 256 + tid) * 8;
    const float4 a = *(const float4*)&x[i];
    const float4 b = *(const float4*)&x[i + 4];
    ushortx8 o;
    o[0] = f2bf(a.x); o[1] = f2bf(a.y); o[2] = f2bf(a.z); o[3] = f2bf(a.w);
    o[4] = f2bf(b.x); o[5] = f2bf(b.y); o[6] = f2bf(b.z); o[7] = f2bf(b.w);
    *(ushortx8*)&xb[i] = o;
    return;
  }
  __shared__ float tile[32][33];
  const int tx = tid & 31, ty = tid >> 5;
  if (gid < 3584) {  // Wqkv transpose
    const int t = gid - 2048;
    const int c0 = (t % 96) * 32, r0 = (t / 96) * 32;
    #pragma unroll
    for (int i = ty; i < 32; i += 8)
      tile[i][tx] = Wqkv[(size_t)(r0 + i) * 3072 + c0 + tx];
    __syncthreads();
    #pragma unroll
    for (int i = ty; i < 32; i += 8) {
      const float sc = (c0 + i < 1024) ? QSCALE : 1.0f;
      wqkvt[(size_t)(c0 + i) * 512 + r0 + tx] = f2bf(tile[tx][i] * sc);
    }
    return;
  }
  if (gid < 4096) {  // Wout transpose
    const int t = gid - 3584;
    const int c0 = (t % 16) * 32, r0 = (t / 16) * 32;
    #pragma unroll
    for (int i = ty; i < 32; i += 8)
      tile[i][tx] = Wout[(size_t)(r0 + i) * 512 + c0 + tx];
    __syncthreads();
    #pragma unroll
    for (int i = ty; i < 32; i += 8)
      woutt[(size_t)(c0 + i) * 1024 + r0 + tx] = f2bf(tile[tx][i]);
    return;
  }
  const int i = (gid - 4096) * 256 + tid;
  if (i < 3072) bq2[i] = bqkv[i] * (i < 1024 ? QSCALE : 1.0f);
}

// ---------------- bf16 GEMM: C = A @ Bt^T + bias, dbuf LDS, counted vmcnt, swizzled ----
// (round-5 double-barrier form; used for the output GEMM, 128x64 tile)
template <int BM, int BN, int BK, int OUT_BF16>
__global__ __launch_bounds__(256, 4) void gemm_bt(const u16* __restrict__ A,
                                                  const u16* __restrict__ Bt,
                                                  const float* __restrict__ bias,
                                                  void* __restrict__ Cv,
                                                  int M, int N, int K) {
  constexpr int RPC = 512 / BK;
  constexpr int LPR = BK / 8;
  constexpr int MASK = LPR - 1;
  constexpr int P = 64 / BK > 0 ? 64 / BK : 1;
  constexpr int CA = BM / RPC, CB = BN / RPC;
  constexpr int CAW = CA / 4, CBW = CB / 4;
  constexpr int VM = CAW + CBW;
  constexpr int FM = BM / 32, FN = BN / 32;
  constexpr int KS = BK / 32;

  __shared__ __attribute__((aligned(16))) u16 As[2][BM * BK];
  __shared__ __attribute__((aligned(16))) u16 Bs[2][BN * BK];
  const int nwg = gridDim.x * gridDim.y;
  int bid = blockIdx.y * gridDim.x + blockIdx.x;
  if ((nwg & 7) == 0) bid = (bid & 7) * (nwg >> 3) + (bid >> 3);
  const int n0 = (bid % gridDim.x) * BN, m0 = (bid / gridDim.x) * BM;
  const int tid = threadIdx.x;
  const int w = tid >> 6, l = tid & 63;
  const int wr = w >> 1, wc = w & 1;
  const int lr = l >> 4, lc = l & 15;
  f32x4 acc[FM][FN] = {};

#define GSTAGE(bi, k0)                                                          \
  do {                                                                          \
    _Pragma("unroll") for (int i = 0; i < CAW; ++i) {                           \
      const int c = w * CAW + i;                                                \
      const int row = c * RPC + l / LPR;                                        \
      const int col = ((l % LPR) ^ ((row / P) & MASK)) * 8;                     \
      gld_lds16(&A[(size_t)(m0 + row) * K + (k0) + col], &As[bi][c * 512]);     \
    }                                                                           \
    _Pragma("unroll") for (int i = 0; i < CBW; ++i) {                           \
      const int c = w * CBW + i;                                                \
      const int row = c * RPC + l / LPR;                                        \
      const int col = ((l % LPR) ^ ((row / P) & MASK)) * 8;                     \
      gld_lds16(&Bt[(size_t)(n0 + row) * K + (k0) + col], &Bs[bi][c * 512]);    \
    }                                                                           \
  } while (0)

#define GCOMP(bi)                                                                      \
  do {                                                                                 \
    _Pragma("unroll") for (int ks = 0; ks < KS; ++ks) {                                \
      bf16x8 af[FM], bfr[FN];                                                          \
      _Pragma("unroll") for (int m = 0; m < FM; ++m) {                                 \
        const int row = wr * (BM / 2) + m * 16 + lc;                                   \
        af[m] = *(const bf16x8*)&As[bi][row * BK +                                     \
                                        (((ks * 4 + lr) ^ ((row / P) & MASK)) << 3)];  \
      }                                                                                \
      _Pragma("unroll") for (int n = 0; n < FN; ++n) {                                 \
        const int row = wc * (BN / 2) + n * 16 + lc;                                   \
        bfr[n] = *(const bf16x8*)&Bs[bi][row * BK +                                    \
                                         (((ks * 4 + lr) ^ ((row / P) & MASK)) << 3)]; \
      }                                                                                \
      __builtin_amdgcn_s_setprio(1);                                                   \
      _Pragma("unroll") for (int m = 0; m < FM; ++m)                                   \
          _Pragma("unroll") for (int n = 0; n < FN; ++n)                               \
              acc[m][n] =                                                              \
          __builtin_amdgcn_mfma_f32_16x16x32_bf16(af[m], bfr[n], acc[m][n], 0, 0, 0);  \
      __builtin_amdgcn_s_setprio(0);                                                   \
    }                                                                                  \
  } while (0)

  GSTAGE(0, 0);
  int buf = 0;
  for (int k0 = BK; k0 < K; k0 += BK) {
    GSTAGE(buf ^ 1, k0);
    if constexpr (VM == 2)
      asm volatile("s_waitcnt vmcnt(2)" ::: "memory");
    else if constexpr (VM == 3)
      asm volatile("s_waitcnt vmcnt(3)" ::: "memory");
    else if constexpr (VM == 4)
      asm volatile("s_waitcnt vmcnt(4)" ::: "memory");
    else
      asm volatile("s_waitcnt vmcnt(8)" ::: "memory");
    __builtin_amdgcn_s_barrier();
    __builtin_amdgcn_sched_barrier(0);
    GCOMP(buf);
    __builtin_amdgcn_s_barrier();
    buf ^= 1;
  }
  asm volatile("s_waitcnt vmcnt(0)" ::: "memory");
  __builtin_amdgcn_s_barrier();
  __builtin_amdgcn_sched_barrier(0);
  GCOMP(buf);
#undef GSTAGE
#undef GCOMP

  #pragma unroll
  for (int n = 0; n < FN; ++n) {
    const int col = n0 + wc * (BN / 2) + n * 16 + lc;
    const float bv = bias[col];
    #pragma unroll
    for (int m = 0; m < FM; ++m) {
      #pragma unroll
      for (int r = 0; r < 4; ++r) {
        const int row = m0 + wr * (BM / 2) + m * 16 + lr * 4 + r;
        const float v = acc[m][n][r] + bv;
        if (OUT_BF16)
          ((u16*)Cv)[(size_t)row * N + col] = f2bf(v);
        else
          ((float*)Cv)[(size_t)row * N + col] = v;
      }
    }
  }
}

// ---------------- 8-phase deep-pipelined bf16 GEMM (QKV): C = A @ Bt^T + bias ------
// (round-5 winner: double-barrier phases, fused Q/K-LDS + V-transposed epilogue)
__global__ __launch_bounds__(512, 2) void gemm_qkv_8ph(const u16* __restrict__ A,
                                                       const u16* __restrict__ Bt,
                                                       const float* __restrict__ bias,
                                                       u16* __restrict__ C,
                                                       u16* __restrict__ vt,
                                                       int M, int N, int K) {
  __shared__ __attribute__((aligned(16))) u16 SMEM[57344];  // 112KB
  u16* const AsP[2] = {SMEM, SMEM + 16384};                 // 2 x 32KB
  u16* const BsP[2] = {SMEM + 32768, SMEM + 45056};         // 2 x 24KB
  const int nwg = gridDim.x;
  int bid = blockIdx.x;
  if ((nwg & 7) == 0) bid = (bid & 7) * (nwg >> 3) + (bid >> 3);
  const int ntile = N / 192;
  const int n0 = (bid % ntile) * 192, m0 = (bid / ntile) * 256;
  const int tid = threadIdx.x;
  const int w = tid >> 6, l = tid & 63;
  const int wr = w >> 2, wc = w & 3;  // 2 x 4 wave grid
  const int lr = l >> 4, lc = l & 15;
  f32x4 acc[8][3] = {};
  bf16x8 af[2][2], bfv[3][2];

#define STAGE_A(bi, kt, h)                                                          \
  do {                                                                              \
    _Pragma("unroll") for (int cc = 0; cc < 2; ++cc) {                              \
      const int cib = (h) * 1024 + (cc * 8 + w) * 64;                               \
      const int ci = cib + l;                                                       \
      const int row = ci >> 3, ck = ci & 7;                                         \
      gld_lds16(&A[(size_t)(m0 + row) * K + (kt) * 64 + ((ck ^ (row & 7)) << 3)],   \
                &AsP[bi][cib * 8]);                                                 \
    }                                                                               \
  } while (0)

#define STAGE_B(bi, kt, t)                                                          \
  do {                                                                              \
    const int cib = (t) * 512 + w * 64;                                             \
    const int ci = cib + l;                                                         \
    const int row = ci >> 3, ck = ci & 7;                                           \
    gld_lds16(&Bt[(size_t)(n0 + row) * K + (kt) * 64 + ((ck ^ (row & 7)) << 3)],    \
              &BsP[bi][cib * 8]);                                                   \
  } while (0)

#define RD_A(bi, mp)                                                                \
  do {                                                                              \
    _Pragma("unroll") for (int m2 = 0; m2 < 2; ++m2)                                \
      _Pragma("unroll") for (int ks = 0; ks < 2; ++ks) {                            \
        const int row = wr * 128 + (2 * (mp) + m2) * 16 + lc;                       \
        af[m2][ks] = *(const bf16x8*)&AsP[bi][row * 64 +                            \
                                              (((ks * 4 + lr) ^ (lc & 7)) << 3)];   \
      }                                                                             \
  } while (0)

#define RD_B(bi)                                                                    \
  do {                                                                              \
    _Pragma("unroll") for (int n = 0; n < 3; ++n)                                   \
      _Pragma("unroll") for (int ks = 0; ks < 2; ++ks) {                            \
        const int row = wc * 48 + n * 16 + lc;                                      \
        bfv[n][ks] = *(const bf16x8*)&BsP[bi][row * 64 +                            \
                                              (((ks * 4 + lr) ^ (lc & 7)) << 3)];   \
      }                                                                             \
  } while (0)

#define MM(mp)                                                                      \
  do {                                                                              \
    __builtin_amdgcn_s_setprio(1);                                                  \
    _Pragma("unroll") for (int m2 = 0; m2 < 2; ++m2)                                \
      _Pragma("unroll") for (int n = 0; n < 3; ++n)                                 \
        _Pragma("unroll") for (int ks = 0; ks < 2; ++ks)                            \
          acc[2 * (mp) + m2][n] = __builtin_amdgcn_mfma_f32_16x16x32_bf16(          \
              af[m2][ks], bfv[n][ks], acc[2 * (mp) + m2][n], 0, 0, 0);              \
    __builtin_amdgcn_s_setprio(0);                                                  \
  } while (0)

#define BARC()                                                                      \
  do {                                                                              \
    __builtin_amdgcn_s_barrier();                                                   \
    asm volatile("s_waitcnt lgkmcnt(0)" ::: "memory");                              \
    __builtin_amdgcn_sched_barrier(0);                                              \
  } while (0)

  // prologue: tile 0 fully (7 gld) + tile 1 B thirds 0,1 (2 gld)
  STAGE_B(0, 0, 0); STAGE_B(0, 0, 1); STAGE_B(0, 0, 2);
  STAGE_A(0, 0, 0); STAGE_A(0, 0, 1);
  STAGE_B(1, 1, 0); STAGE_B(1, 1, 1);
  asm volatile("s_waitcnt vmcnt(2)" ::: "memory");
  __builtin_amdgcn_s_barrier();
  __builtin_amdgcn_sched_barrier(0);

  const int NI = K >> 7;  // 2 K-tiles of 64 per iteration
  for (int i = 0; i < NI; ++i) {
    const bool nl = (i < NI - 1);
    const int tO = 2 * i + 1, tE2 = 2 * i + 2, tO2 = 2 * i + 3;
    // ---- p0: even-tile quadrant 0; finish staging this iter's odd tile
    RD_B(0); RD_A(0, 0);
    STAGE_B(1, tO, 2); STAGE_A(1, tO, 0); STAGE_A(1, tO, 1);
    BARC(); MM(0);
    __builtin_amdgcn_s_barrier();
    // ---- p1
    RD_A(0, 1);
    if (nl) STAGE_B(0, tE2, 0);
    BARC(); MM(1);
    __builtin_amdgcn_s_barrier();
    // ---- p2
    RD_A(0, 2);
    if (nl) STAGE_B(0, tE2, 1);
    BARC(); MM(2);
    __builtin_amdgcn_s_barrier();
    // ---- p3 + odd-tile gate
    RD_A(0, 3);
    if (nl) STAGE_B(0, tE2, 2);
    BARC(); MM(3);
    if (nl) asm volatile("s_waitcnt vmcnt(3)" ::: "memory");
    else    asm volatile("s_waitcnt vmcnt(0)" ::: "memory");
    __builtin_amdgcn_s_barrier();
    __builtin_amdgcn_sched_barrier(0);
    // ---- p4: odd-tile quadrant 0
    RD_B(1); RD_A(1, 0);
    if (nl) STAGE_A(0, tE2, 0);
    BARC(); MM(0);
    __builtin_amdgcn_s_barrier();
    // ---- p5
    RD_A(1, 1);
    if (nl) STAGE_A(0, tE2, 1);
    BARC(); MM(1);
    __builtin_amdgcn_s_barrier();
    // ---- p6
    RD_A(1, 2);
    if (nl) STAGE_B(1, tO2, 0);
    BARC(); MM(2);
    __builtin_amdgcn_s_barrier();
    // ---- p7 + even-tile gate
    RD_A(1, 3);
    if (nl) STAGE_B(1, tO2, 1);
    BARC(); MM(3);
    if (nl) {
      asm volatile("s_waitcnt vmcnt(2)" ::: "memory");
      __builtin_amdgcn_s_barrier();
      __builtin_amdgcn_sched_barrier(0);
    }
  }
#undef STAGE_A
#undef STAGE_B
#undef RD_A
#undef RD_B
#undef MM
#undef BARC

  // ---- epilogue: Q/K via LDS coalesced store; V transposed direct to vtb ----
  __builtin_amdgcn_s_barrier();
  const int b_idx = m0 >> 10;     // batch (0..7)
  const int tok0 = m0 & 1023;     // token base within batch
  #pragma unroll
  for (int n = 0; n < 3; ++n) {
    const int gc = n0 + wc * 48 + n * 16 + lc;  // frag-uniform region (16 | 2048)
    const float bv = bias[gc];
    if (gc < 2048) {
      #pragma unroll
      for (int m = 0; m < 8; ++m)
        #pragma unroll
        for (int r = 0; r < 4; ++r) {
          const int row = wr * 128 + m * 16 + lr * 4 + r;
          SMEM[row * 192 + wc * 48 + n * 16 + lc] = f2bf(acc[m][n][r] + bv);
        }
    } else {
      const int hd = gc - 2048;
      u16* vrow = vt + ((size_t)(b_idx * 8 + (hd >> 7)) * 128 + (hd & 127)) * 1024;
      #pragma unroll
      for (int m = 0; m < 8; ++m) {
        const int tok = tok0 + wr * 128 + m * 16 + lr * 4;
        ushortx4 o;
        o[0] = f2bf(acc[m][n][0] + bv);
        o[1] = f2bf(acc[m][n][1] + bv);
        o[2] = f2bf(acc[m][n][2] + bv);
        o[3] = f2bf(acc[m][n][3] + bv);
        *(ushortx4*)&vrow[tok] = o;
      }
    }
  }
  __builtin_amdgcn_s_barrier();
  #pragma unroll
  for (int it = 0; it < 12; ++it) {
    const int chunk = it * 512 + tid;      // 6144 x 16B chunks
    const int row = chunk / 24, c16 = chunk % 24;
    if (n0 + c16 * 8 < 2048) {
      const bf16x8 v = *(const bf16x8*)&SMEM[row * 192 + c16 * 8];
      *(bf16x8*)&C[(size_t)(m0 + row) * N + n0 + c16 * 8] = v;
    }
  }
}

// ---------------- flash attention: no-LDS, zero-barrier, direct L2 operand reads ----
// m169 lesson (Common-mistake #7): at S=1024, K/V (256KB each per head) is
// L2-resident -- LDS staging is pure overhead. Each wave reads K/V fragments
// directly from global (L1/L2) as MFMA operands; NO LDS, NO barriers, waves fully
// independent -> compiler pipelines loads across tiles, waves de-phase naturally.
// Addresses are the deswizzled forms of the old LDS layout (verified symbolically):
//   ak = K[(t*64 + ll(+32))*3072 + s*16 + hi*8]
//   bv = V[(db*32 + ll)*1024 + t*64 + (kb*4 + s2*2 + hi)*8]
__global__ __launch_bounds__(256, 2) void attn_fwd(const u16* __restrict__ qkv,
                                                   const u16* __restrict__ vt,
                                                   u16* __restrict__ attn_out) {
  // XCD swizzle: 512 blocks -> all 8 q-blocks of one (b,h) land on one XCD
  const int orig = blockIdx.y * 8 + blockIdx.x;
  const int swz = (orig & 7) * 64 + (orig >> 3);
  const int bh = swz >> 3, b = bh >> 3, h = bh & 7;
  const int q0 = (swz & 7) * 128;
  const int tid = threadIdx.x, w = tid >> 6, l = tid & 63;
  const int ll = l & 31, hi = l >> 5;
  const int wq0 = q0 + w * 32;
  const u16* Qb = qkv + (size_t)(b * 1024 + wq0) * 3072 + h * 128;
  const u16* Kb = qkv + (size_t)(b * 1024) * 3072 + 1024 + h * 128;
  const u16* Vb = vt + (size_t)(b * 8 + h) * 128 * 1024;

  bf16x8 bq[8];
  #pragma unroll
  for (int s = 0; s < 8; ++s)
    bq[s] = *(const bf16x8*)&Qb[(size_t)ll * 3072 + s * 16 + hi * 8];

  bf16x8 ones;
  #pragma unroll
  for (int i = 0; i < 8; ++i) ones[i] = (__bf16)1.0f;
  const f32x16 fz = {};  // persistent zero C operand

  // per-lane base pointers
  const u16* kr0 = Kb + (size_t)ll * 3072 + hi * 8;         // + t*196608 + s*16
  const u16* kr1 = Kb + (size_t)(ll + 32) * 3072 + hi * 8;
  const u16* vr0 = Vb + (size_t)ll * 1024 + hi * 8;         // + db*32768 + t*64 + (kb*4+s2*2)*8

  f32x16 acc_o[4] = {};
  f32x16 acc_l = {};
  f32x16 st0, st1;
  u32 mm[16];

  for (int t = 0; t < 16; ++t) {
    const size_t kofs = (size_t)t * 196608;
    // ---- QK: K operands straight from L1/L2 ----
    {
      const bf16x8 a0 = *(const bf16x8*)&kr0[kofs];
      const bf16x8 a1 = *(const bf16x8*)&kr1[kofs];
      st0 = __builtin_amdgcn_mfma_f32_32x32x16_bf16(a0, bq[0], fz, 0, 0, 0);
      st1 = __builtin_amdgcn_mfma_f32_32x32x16_bf16(a1, bq[0], fz, 0, 0, 0);
    }
    #pragma unroll
    for (int s = 1; s < 8; ++s) {
      const bf16x8 ak0 = *(const bf16x8*)&kr0[kofs + s * 16];
      const bf16x8 ak1 = *(const bf16x8*)&kr1[kofs + s * 16];
      st0 = __builtin_amdgcn_mfma_f32_32x32x16_bf16(ak0, bq[s], st0, 0, 0, 0);
      st1 = __builtin_amdgcn_mfma_f32_32x32x16_bf16(ak1, bq[s], st1, 0, 0, 0);
    }
    // ---- softmax (log2-domain scores; scale folded into W_qkv/b_qkv) ----
    #pragma unroll
    for (int kb = 0; kb < 2; ++kb) {
      float pe[16];
      #pragma unroll
      for (int r = 0; r < 16; ++r)
        pe[r] = __builtin_amdgcn_exp2f(kb ? st1[r] : st0[r]);
      #pragma unroll
      for (int j = 0; j < 8; ++j) {
        u32 d_;
        asm("v_cvt_pk_bf16_f32 %0, %1, %2"
            : "=v"(d_)
            : "v"(pe[2 * j]), "v"(pe[2 * j + 1]));
        mm[kb * 8 + j] = d_;
      }
      asm volatile("v_permlane32_swap_b32 %0, %1"
                   : "+v"(mm[kb * 8 + 0]), "+v"(mm[kb * 8 + 2]));
      asm volatile("v_permlane32_swap_b32 %0, %1"
                   : "+v"(mm[kb * 8 + 1]), "+v"(mm[kb * 8 + 3]));
      asm volatile("v_permlane32_swap_b32 %0, %1"
                   : "+v"(mm[kb * 8 + 4]), "+v"(mm[kb * 8 + 6]));
      asm volatile("v_permlane32_swap_b32 %0, %1"
                   : "+v"(mm[kb * 8 + 5]), "+v"(mm[kb * 8 + 7]));
    }
    // ---- PV: V operands straight from L1/L2 ----
    #pragma unroll
    for (int kb = 0; kb < 2; ++kb) {
      #pragma unroll
      for (int s2 = 0; s2 < 2; ++s2) {
        union { u32 u[4]; bf16x8 v; } pu;
        pu.u[0] = mm[kb * 8 + s2 * 4 + 0];
        pu.u[1] = mm[kb * 8 + s2 * 4 + 1];
        pu.u[2] = mm[kb * 8 + s2 * 4 + 2];
        pu.u[3] = mm[kb * 8 + s2 * 4 + 3];
        const bf16x8 pa = pu.v;
        acc_l = __builtin_amdgcn_mfma_f32_32x32x16_bf16(pa, ones, acc_l, 0, 0, 0);
        #pragma unroll
        for (int db = 0; db < 4; ++db) {
          const bf16x8 bv = *(const bf16x8*)&vr0[(size_t)db * 32768 + t * 64 +
                                                 (kb * 4 + s2 * 2) * 8];
          acc_o[db] =
              __builtin_amdgcn_mfma_f32_32x32x16_bf16(pa, bv, acc_o[db], 0, 0, 0);
        }
      }
    }
  }

  float inv[16];
  #pragma unroll
  for (int r = 0; r < 16; ++r) inv[r] = __builtin_amdgcn_rcpf(acc_l[r]);
  u16* Ob = attn_out + (size_t)(b * 1024 + wq0) * 1024 + h * 128;
  #pragma unroll
  for (int db = 0; db < 4; ++db)
    #pragma unroll
    for (int r = 0; r < 16; ++r) {
      const int q = (r & 3) + 8 * (r >> 2) + 4 * hi;
      Ob[(size_t)q * 1024 + db * 32 + ll] = f2bf(acc_o[db][r] * inv[r]);
    }
}

extern "C" void kernel_launch(void* const* d_in, const int* in_sizes, int n_in,
                              void* d_out, int out_size, void* d_ws, size_t ws_size,
                              hipStream_t stream) {
  const float* x = (const float*)d_in[0];      // (2,4,1024,512)
  const float* Wqkv = (const float*)d_in[1];   // (512,3072)
  const float* bqkv = (const float*)d_in[2];   // (3072,)
  const float* Wout = (const float*)d_in[3];   // (1024,512)
  const float* bout = (const float*)d_in[4];   // (512,)
  float* out = (float*)d_out;                  // (2,4,1024,512) fp32

  char* ws = (char*)d_ws;
  u16* xb    = (u16*)(ws);                         // 8192*512   bf16 (8.0 MB)
  u16* wqkvt = (u16*)(ws + 8388608);               // 3072*512   bf16 (3.0 MB)
  u16* woutt = (u16*)(ws + 8388608 + 3145728);     // 512*1024   bf16 (1.0 MB)
  u16* qkvb  = (u16*)(ws + 12582912);              // 8192*3072  bf16 (48 MB; V third unused)
  u16* vtb   = (u16*)(ws + 62914560);              // 64*128*1024 bf16 (16 MB)
  u16* aob   = (u16*)(ws + 79691776);              // 8192*1024  bf16 (16 MB)
  float* bq2 = (float*)aob;                        // 3072 f32 (12 KB; consumed pre-attn)

  prep_fused<<<4108, 256, 0, stream>>>(x, xb, bqkv, bq2, Wqkv, wqkvt, Wout, woutt);

  // QKV = x @ W_qkv + b_qkv; Q/K -> qkvb, V -> vtb transposed (fused)
  gemm_qkv_8ph<<<dim3(512), 512, 0, stream>>>(xb, wqkvt, bq2, qkvb, vtb,
                                              8192, 3072, 512);

  // no-LDS zero-barrier attention: K/V read directly through L1/L2
  attn_fwd<<<dim3(8, 64), 256, 0, stream>>>(qkvb, vtb, aob);

  // out = attn_out @ W_out + b_out  (M=8192, N=512, K=1024), fp32 out
  gemm_bt<128, 64, 32, 0><<<dim3(8, 64), 256, 0, stream>>>(aob, woutt, bout, out,
                                                           8192, 512, 1024);
}

// Round 11
// 110.888 us; speedup vs baseline: 1.8194x; 1.8194x over previous
//
#include <hip/hip_runtime.h>

typedef __attribute__((ext_vector_type(4))) float f32x4;
typedef __attribute__((ext_vector_type(16))) float f32x16;
typedef __attribute__((ext_vector_type(8))) __bf16 bf16x8;
typedef __attribute__((ext_vector_type(8))) unsigned short ushortx8;
typedef __attribute__((ext_vector_type(4))) unsigned short ushortx4;
typedef unsigned short u16;
typedef unsigned int u32;

#define AS1 __attribute__((address_space(1)))
#define AS3 __attribute__((address_space(3)))

__device__ __forceinline__ void gld_lds16(const void* g, void* s) {
  __builtin_amdgcn_global_load_lds((AS1 void*)g, (AS3 void*)s, 16, 0, 0);
}

__device__ __forceinline__ u16 f2bf(float f) {
  unsigned int u = __float_as_uint(f);
  unsigned int r = (u + 0x7FFFu + ((u >> 16) & 1u)) >> 16;
  return (u16)r;
}

// 0.125 * log2(e): folded into Q columns of W_qkv/b_qkv so QK^T scores are log2-domain
#define QSCALE 0.1803368801111244f

// ---------------- fused prep: cvt x->bf16 | transpose Wqkv | transpose Wout | bias ----
__global__ __launch_bounds__(256) void prep_fused(
    const float* __restrict__ x, u16* __restrict__ xb,
    const float* __restrict__ bqkv, float* __restrict__ bq2,
    const float* __restrict__ Wqkv, u16* __restrict__ wqkvt,
    const float* __restrict__ Wout, u16* __restrict__ woutt) {
  const int gid = blockIdx.x, tid = threadIdx.x;
  if (gid < 2048) {
    const int i = (gid * 256 + tid) * 8;
    const float4 a = *(const float4*)&x[i];
    const float4 b = *(const float4*)&x[i + 4];
    ushortx8 o;
    o[0] = f2bf(a.x); o[1] = f2bf(a.y); o[2] = f2bf(a.z); o[3] = f2bf(a.w);
    o[4] = f2bf(b.x); o[5] = f2bf(b.y); o[6] = f2bf(b.z); o[7] = f2bf(b.w);
    *(ushortx8*)&xb[i] = o;
    return;
  }
  __shared__ float tile[32][33];
  const int tx = tid & 31, ty = tid >> 5;
  if (gid < 3584) {  // Wqkv transpose
    const int t = gid - 2048;
    const int c0 = (t % 96) * 32, r0 = (t / 96) * 32;
    #pragma unroll
    for (int i = ty; i < 32; i += 8)
      tile[i][tx] = Wqkv[(size_t)(r0 + i) * 3072 + c0 + tx];
    __syncthreads();
    #pragma unroll
    for (int i = ty; i < 32; i += 8) {
      const float sc = (c0 + i < 1024) ? QSCALE : 1.0f;
      wqkvt[(size_t)(c0 + i) * 512 + r0 + tx] = f2bf(tile[tx][i] * sc);
    }
    return;
  }
  if (gid < 4096) {  // Wout transpose
    const int t = gid - 3584;
    const int c0 = (t % 16) * 32, r0 = (t / 16) * 32;
    #pragma unroll
    for (int i = ty; i < 32; i += 8)
      tile[i][tx] = Wout[(size_t)(r0 + i) * 512 + c0 + tx];
    __syncthreads();
    #pragma unroll
    for (int i = ty; i < 32; i += 8)
      woutt[(size_t)(c0 + i) * 1024 + r0 + tx] = f2bf(tile[tx][i]);
    return;
  }
  const int i = (gid - 4096) * 256 + tid;
  if (i < 3072) bq2[i] = bqkv[i] * (i < 1024 ? QSCALE : 1.0f);
}

// ---------------- bf16 GEMM: C = A @ Bt^T + bias, dbuf LDS, counted vmcnt, swizzled ----
// (round-5 double-barrier form; used for the output GEMM, 128x64 tile)
template <int BM, int BN, int BK, int OUT_BF16>
__global__ __launch_bounds__(256, 4) void gemm_bt(const u16* __restrict__ A,
                                                  const u16* __restrict__ Bt,
                                                  const float* __restrict__ bias,
                                                  void* __restrict__ Cv,
                                                  int M, int N, int K) {
  constexpr int RPC = 512 / BK;
  constexpr int LPR = BK / 8;
  constexpr int MASK = LPR - 1;
  constexpr int P = 64 / BK > 0 ? 64 / BK : 1;
  constexpr int CA = BM / RPC, CB = BN / RPC;
  constexpr int CAW = CA / 4, CBW = CB / 4;
  constexpr int VM = CAW + CBW;
  constexpr int FM = BM / 32, FN = BN / 32;
  constexpr int KS = BK / 32;

  __shared__ __attribute__((aligned(16))) u16 As[2][BM * BK];
  __shared__ __attribute__((aligned(16))) u16 Bs[2][BN * BK];
  const int nwg = gridDim.x * gridDim.y;
  int bid = blockIdx.y * gridDim.x + blockIdx.x;
  if ((nwg & 7) == 0) bid = (bid & 7) * (nwg >> 3) + (bid >> 3);
  const int n0 = (bid % gridDim.x) * BN, m0 = (bid / gridDim.x) * BM;
  const int tid = threadIdx.x;
  const int w = tid >> 6, l = tid & 63;
  const int wr = w >> 1, wc = w & 1;
  const int lr = l >> 4, lc = l & 15;
  f32x4 acc[FM][FN] = {};

#define GSTAGE(bi, k0)                                                          \
  do {                                                                          \
    _Pragma("unroll") for (int i = 0; i < CAW; ++i) {                           \
      const int c = w * CAW + i;                                                \
      const int row = c * RPC + l / LPR;                                        \
      const int col = ((l % LPR) ^ ((row / P) & MASK)) * 8;                     \
      gld_lds16(&A[(size_t)(m0 + row) * K + (k0) + col], &As[bi][c * 512]);     \
    }                                                                           \
    _Pragma("unroll") for (int i = 0; i < CBW; ++i) {                           \
      const int c = w * CBW + i;                                                \
      const int row = c * RPC + l / LPR;                                        \
      const int col = ((l % LPR) ^ ((row / P) & MASK)) * 8;                     \
      gld_lds16(&Bt[(size_t)(n0 + row) * K + (k0) + col], &Bs[bi][c * 512]);    \
    }                                                                           \
  } while (0)

#define GCOMP(bi)                                                                      \
  do {                                                                                 \
    _Pragma("unroll") for (int ks = 0; ks < KS; ++ks) {                                \
      bf16x8 af[FM], bfr[FN];                                                          \
      _Pragma("unroll") for (int m = 0; m < FM; ++m) {                                 \
        const int row = wr * (BM / 2) + m * 16 + lc;                                   \
        af[m] = *(const bf16x8*)&As[bi][row * BK +                                     \
                                        (((ks * 4 + lr) ^ ((row / P) & MASK)) << 3)];  \
      }                                                                                \
      _Pragma("unroll") for (int n = 0; n < FN; ++n) {                                 \
        const int row = wc * (BN / 2) + n * 16 + lc;                                   \
        bfr[n] = *(const bf16x8*)&Bs[bi][row * BK +                                    \
                                         (((ks * 4 + lr) ^ ((row / P) & MASK)) << 3)]; \
      }                                                                                \
      __builtin_amdgcn_s_setprio(1);                                                   \
      _Pragma("unroll") for (int m = 0; m < FM; ++m)                                   \
          _Pragma("unroll") for (int n = 0; n < FN; ++n)                               \
              acc[m][n] =                                                              \
          __builtin_amdgcn_mfma_f32_16x16x32_bf16(af[m], bfr[n], acc[m][n], 0, 0, 0);  \
      __builtin_amdgcn_s_setprio(0);                                                   \
    }                                                                                  \
  } while (0)

  GSTAGE(0, 0);
  int buf = 0;
  for (int k0 = BK; k0 < K; k0 += BK) {
    GSTAGE(buf ^ 1, k0);
    if constexpr (VM == 2)
      asm volatile("s_waitcnt vmcnt(2)" ::: "memory");
    else if constexpr (VM == 3)
      asm volatile("s_waitcnt vmcnt(3)" ::: "memory");
    else if constexpr (VM == 4)
      asm volatile("s_waitcnt vmcnt(4)" ::: "memory");
    else
      asm volatile("s_waitcnt vmcnt(8)" ::: "memory");
    __builtin_amdgcn_s_barrier();
    __builtin_amdgcn_sched_barrier(0);
    GCOMP(buf);
    __builtin_amdgcn_s_barrier();
    buf ^= 1;
  }
  asm volatile("s_waitcnt vmcnt(0)" ::: "memory");
  __builtin_amdgcn_s_barrier();
  __builtin_amdgcn_sched_barrier(0);
  GCOMP(buf);
#undef GSTAGE
#undef GCOMP

  #pragma unroll
  for (int n = 0; n < FN; ++n) {
    const int col = n0 + wc * (BN / 2) + n * 16 + lc;
    const float bv = bias[col];
    #pragma unroll
    for (int m = 0; m < FM; ++m) {
      #pragma unroll
      for (int r = 0; r < 4; ++r) {
        const int row = m0 + wr * (BM / 2) + m * 16 + lr * 4 + r;
        const float v = acc[m][n][r] + bv;
        if (OUT_BF16)
          ((u16*)Cv)[(size_t)row * N + col] = f2bf(v);
        else
          ((float*)Cv)[(size_t)row * N + col] = v;
      }
    }
  }
}

// ---------------- 8-phase deep-pipelined bf16 GEMM (QKV): C = A @ Bt^T + bias ------
// (round-5 winner: double-barrier phases, fused Q/K-LDS + V-transposed epilogue)
__global__ __launch_bounds__(512, 2) void gemm_qkv_8ph(const u16* __restrict__ A,
                                                       const u16* __restrict__ Bt,
                                                       const float* __restrict__ bias,
                                                       u16* __restrict__ C,
                                                       u16* __restrict__ vt,
                                                       int M, int N, int K) {
  __shared__ __attribute__((aligned(16))) u16 SMEM[57344];  // 112KB
  u16* const AsP[2] = {SMEM, SMEM + 16384};                 // 2 x 32KB
  u16* const BsP[2] = {SMEM + 32768, SMEM + 45056};         // 2 x 24KB
  const int nwg = gridDim.x;
  int bid = blockIdx.x;
  if ((nwg & 7) == 0) bid = (bid & 7) * (nwg >> 3) + (bid >> 3);
  const int ntile = N / 192;
  const int n0 = (bid % ntile) * 192, m0 = (bid / ntile) * 256;
  const int tid = threadIdx.x;
  const int w = tid >> 6, l = tid & 63;
  const int wr = w >> 2, wc = w & 3;  // 2 x 4 wave grid
  const int lr = l >> 4, lc = l & 15;
  f32x4 acc[8][3] = {};
  bf16x8 af[2][2], bfv[3][2];

#define STAGE_A(bi, kt, h)                                                          \
  do {                                                                              \
    _Pragma("unroll") for (int cc = 0; cc < 2; ++cc) {                              \
      const int cib = (h) * 1024 + (cc * 8 + w) * 64;                               \
      const int ci = cib + l;                                                       \
      const int row = ci >> 3, ck = ci & 7;                                         \
      gld_lds16(&A[(size_t)(m0 + row) * K + (kt) * 64 + ((ck ^ (row & 7)) << 3)],   \
                &AsP[bi][cib * 8]);                                                 \
    }                                                                               \
  } while (0)

#define STAGE_B(bi, kt, t)                                                          \
  do {                                                                              \
    const int cib = (t) * 512 + w * 64;                                             \
    const int ci = cib + l;                                                         \
    const int row = ci >> 3, ck = ci & 7;                                           \
    gld_lds16(&Bt[(size_t)(n0 + row) * K + (kt) * 64 + ((ck ^ (row & 7)) << 3)],    \
              &BsP[bi][cib * 8]);                                                   \
  } while (0)

#define RD_A(bi, mp)                                                                \
  do {                                                                              \
    _Pragma("unroll") for (int m2 = 0; m2 < 2; ++m2)                                \
      _Pragma("unroll") for (int ks = 0; ks < 2; ++ks) {                            \
        const int row = wr * 128 + (2 * (mp) + m2) * 16 + lc;                       \
        af[m2][ks] = *(const bf16x8*)&AsP[bi][row * 64 +                            \
                                              (((ks * 4 + lr) ^ (lc & 7)) << 3)];   \
      }                                                                             \
  } while (0)

#define RD_B(bi)                                                                    \
  do {                                                                              \
    _Pragma("unroll") for (int n = 0; n < 3; ++n)                                   \
      _Pragma("unroll") for (int ks = 0; ks < 2; ++ks) {                            \
        const int row = wc * 48 + n * 16 + lc;                                      \
        bfv[n][ks] = *(const bf16x8*)&BsP[bi][row * 64 +                            \
                                              (((ks * 4 + lr) ^ (lc & 7)) << 3)];   \
      }                                                                             \
  } while (0)

#define MM(mp)                                                                      \
  do {                                                                              \
    __builtin_amdgcn_s_setprio(1);                                                  \
    _Pragma("unroll") for (int m2 = 0; m2 < 2; ++m2)                                \
      _Pragma("unroll") for (int n = 0; n < 3; ++n)                                 \
        _Pragma("unroll") for (int ks = 0; ks < 2; ++ks)                            \
          acc[2 * (mp) + m2][n] = __builtin_amdgcn_mfma_f32_16x16x32_bf16(          \
              af[m2][ks], bfv[n][ks], acc[2 * (mp) + m2][n], 0, 0, 0);              \
    __builtin_amdgcn_s_setprio(0);                                                  \
  } while (0)

#define BARC()                                                                      \
  do {                                                                              \
    __builtin_amdgcn_s_barrier();                                                   \
    asm volatile("s_waitcnt lgkmcnt(0)" ::: "memory");                              \
    __builtin_amdgcn_sched_barrier(0);                                              \
  } while (0)

  // prologue: tile 0 fully (7 gld) + tile 1 B thirds 0,1 (2 gld)
  STAGE_B(0, 0, 0); STAGE_B(0, 0, 1); STAGE_B(0, 0, 2);
  STAGE_A(0, 0, 0); STAGE_A(0, 0, 1);
  STAGE_B(1, 1, 0); STAGE_B(1, 1, 1);
  asm volatile("s_waitcnt vmcnt(2)" ::: "memory");
  __builtin_amdgcn_s_barrier();
  __builtin_amdgcn_sched_barrier(0);

  const int NI = K >> 7;  // 2 K-tiles of 64 per iteration
  for (int i = 0; i < NI; ++i) {
    const bool nl = (i < NI - 1);
    const int tO = 2 * i + 1, tE2 = 2 * i + 2, tO2 = 2 * i + 3;
    // ---- p0: even-tile quadrant 0; finish staging this iter's odd tile
    RD_B(0); RD_A(0, 0);
    STAGE_B(1, tO, 2); STAGE_A(1, tO, 0); STAGE_A(1, tO, 1);
    BARC(); MM(0);
    __builtin_amdgcn_s_barrier();
    // ---- p1
    RD_A(0, 1);
    if (nl) STAGE_B(0, tE2, 0);
    BARC(); MM(1);
    __builtin_amdgcn_s_barrier();
    // ---- p2
    RD_A(0, 2);
    if (nl) STAGE_B(0, tE2, 1);
    BARC(); MM(2);
    __builtin_amdgcn_s_barrier();
    // ---- p3 + odd-tile gate
    RD_A(0, 3);
    if (nl) STAGE_B(0, tE2, 2);
    BARC(); MM(3);
    if (nl) asm volatile("s_waitcnt vmcnt(3)" ::: "memory");
    else    asm volatile("s_waitcnt vmcnt(0)" ::: "memory");
    __builtin_amdgcn_s_barrier();
    __builtin_amdgcn_sched_barrier(0);
    // ---- p4: odd-tile quadrant 0
    RD_B(1); RD_A(1, 0);
    if (nl) STAGE_A(0, tE2, 0);
    BARC(); MM(0);
    __builtin_amdgcn_s_barrier();
    // ---- p5
    RD_A(1, 1);
    if (nl) STAGE_A(0, tE2, 1);
    BARC(); MM(1);
    __builtin_amdgcn_s_barrier();
    // ---- p6
    RD_A(1, 2);
    if (nl) STAGE_B(1, tO2, 0);
    BARC(); MM(2);
    __builtin_amdgcn_s_barrier();
    // ---- p7 + even-tile gate
    RD_A(1, 3);
    if (nl) STAGE_B(1, tO2, 1);
    BARC(); MM(3);
    if (nl) {
      asm volatile("s_waitcnt vmcnt(2)" ::: "memory");
      __builtin_amdgcn_s_barrier();
      __builtin_amdgcn_sched_barrier(0);
    }
  }
#undef STAGE_A
#undef STAGE_B
#undef RD_A
#undef RD_B
#undef MM
#undef BARC

  // ---- epilogue: Q/K via LDS coalesced store; V transposed direct to vtb ----
  __builtin_amdgcn_s_barrier();
  const int b_idx = m0 >> 10;     // batch (0..7)
  const int tok0 = m0 & 1023;     // token base within batch
  #pragma unroll
  for (int n = 0; n < 3; ++n) {
    const int gc = n0 + wc * 48 + n * 16 + lc;  // frag-uniform region (16 | 2048)
    const float bv = bias[gc];
    if (gc < 2048) {
      #pragma unroll
      for (int m = 0; m < 8; ++m)
        #pragma unroll
        for (int r = 0; r < 4; ++r) {
          const int row = wr * 128 + m * 16 + lr * 4 + r;
          SMEM[row * 192 + wc * 48 + n * 16 + lc] = f2bf(acc[m][n][r] + bv);
        }
    } else {
      const int hd = gc - 2048;
      u16* vrow = vt + ((size_t)(b_idx * 8 + (hd >> 7)) * 128 + (hd & 127)) * 1024;
      #pragma unroll
      for (int m = 0; m < 8; ++m) {
        const int tok = tok0 + wr * 128 + m * 16 + lr * 4;
        ushortx4 o;
        o[0] = f2bf(acc[m][n][0] + bv);
        o[1] = f2bf(acc[m][n][1] + bv);
        o[2] = f2bf(acc[m][n][2] + bv);
        o[3] = f2bf(acc[m][n][3] + bv);
        *(ushortx4*)&vrow[tok] = o;
      }
    }
  }
  __builtin_amdgcn_s_barrier();
  #pragma unroll
  for (int it = 0; it < 12; ++it) {
    const int chunk = it * 512 + tid;      // 6144 x 16B chunks
    const int row = chunk / 24, c16 = chunk % 24;
    if (n0 + c16 * 8 < 2048) {
      const bf16x8 v = *(const bf16x8*)&SMEM[row * 192 + c16 * 8];
      *(bf16x8*)&C[(size_t)(m0 + row) * N + n0 + c16 * 8] = v;
    }
  }
}

// ---------------- flash attention: 32x32x16 MFMA, P in regs, counted-vmcnt pipeline ---
// Round-5 proven structure (54.5-55.4 us): dbuf LDS staging (the staging IS the
// coalescer -- r10's direct-global reads were 64-lines-per-load, 2.6x slower),
// counted vmcnt(8) keeps next-tile DMA in flight across the compute barrier.
// Micro-opts carried from r8 (verified neutral-positive): zero-C hoisted into the
// first QK MFMA; exp2 via builtin.
__global__ __launch_bounds__(256, 2) void attn_fwd(const u16* __restrict__ qkv,
                                                   const u16* __restrict__ vt,
                                                   u16* __restrict__ attn_out) {
  __shared__ __attribute__((aligned(16))) u16 Ks[2][64 * 128];
  __shared__ __attribute__((aligned(16))) u16 Vs[2][64 * 128];
  // XCD swizzle: 512 blocks -> each XCD owns 8 consecutive heads
  const int orig = blockIdx.y * 8 + blockIdx.x;
  const int swz = (orig & 7) * 64 + (orig >> 3);
  const int bh = swz >> 3, b = bh >> 3, h = bh & 7;
  const int q0 = (swz & 7) * 128;
  const int tid = threadIdx.x, w = tid >> 6, l = tid & 63;
  const int ll = l & 31, hi = l >> 5;
  const int wq0 = q0 + w * 32;
  const u16* Qb = qkv + (size_t)(b * 1024 + wq0) * 3072 + h * 128;
  const u16* Kb = qkv + (size_t)(b * 1024) * 3072 + 1024 + h * 128;
  const u16* Vb = vt + (size_t)(b * 8 + h) * 128 * 1024;

  bf16x8 bq[8];
  #pragma unroll
  for (int s = 0; s < 8; ++s)
    bq[s] = *(const bf16x8*)&Qb[(size_t)ll * 3072 + s * 16 + hi * 8];
  asm volatile("s_waitcnt vmcnt(0)" ::: "memory");  // bq resident; vmcnt clean

  bf16x8 ones;
  #pragma unroll
  for (int i = 0; i < 8; ++i) ones[i] = (__bf16)1.0f;
  const f32x16 fz = {};  // persistent zero C operand

  const u16* sb[8];
  int dst0;
  if (w < 2) {
    #pragma unroll
    for (int j = 0; j < 8; ++j) {
      const int r = w * 32 + j * 4 + (l >> 4);
      const int c = l & 15;
      sb[j] = Kb + (size_t)r * 3072 + ((c ^ (r & 15)) << 3);
    }
    dst0 = w * 4096;
  } else {
    #pragma unroll
    for (int j = 0; j < 8; ++j) {
      const int r2 = (w - 2) * 32 + j * 4 + (l >> 4);
      const int c = l & 15;
      const int d = ((c >> 3) ^ ((r2 >> 3) & 1)) * 64 + (r2 >> 5) * 32 + (r2 & 31);
      const int kc = (c & 7) ^ (r2 & 7);
      sb[j] = Vb + (size_t)d * 1024 + (kc << 3);
    }
    dst0 = (w - 2) * 4096;
  }

#define STAGE(bi, tt)                                                            \
  do {                                                                           \
    if (w < 2) {                                                                 \
      _Pragma("unroll") for (int j = 0; j < 8; ++j)                              \
          gld_lds16(sb[j] + (size_t)(tt)*196608, &Ks[bi][dst0 + j * 512]);       \
    } else {                                                                     \
      _Pragma("unroll") for (int j = 0; j < 8; ++j)                              \
          gld_lds16(sb[j] + (size_t)(tt)*64, &Vs[bi][dst0 + j * 512]);           \
    }                                                                            \
  } while (0)

#define QK(Kt)                                                                     \
  do {                                                                            \
    __builtin_amdgcn_s_setprio(1);                                                \
    {                                                                             \
      const int ch = (hi ^ (ll & 15)) << 3;                                       \
      const bf16x8 a0 = *(const bf16x8*)&(Kt)[ll * 128 + ch];                     \
      const bf16x8 a1 = *(const bf16x8*)&(Kt)[(32 + ll) * 128 + ch];              \
      st0 = __builtin_amdgcn_mfma_f32_32x32x16_bf16(a0, bq[0], fz, 0, 0, 0);      \
      st1 = __builtin_amdgcn_mfma_f32_32x32x16_bf16(a1, bq[0], fz, 0, 0, 0);      \
    }                                                                             \
    _Pragma("unroll") for (int s = 1; s < 8; ++s) {                               \
      const int ch = ((s * 2 + hi) ^ (ll & 15)) << 3;                             \
      const bf16x8 ak0 = *(const bf16x8*)&(Kt)[ll * 128 + ch];                    \
      const bf16x8 ak1 = *(const bf16x8*)&(Kt)[(32 + ll) * 128 + ch];             \
      st0 = __builtin_amdgcn_mfma_f32_32x32x16_bf16(ak0, bq[s], st0, 0, 0, 0);    \
      st1 = __builtin_amdgcn_mfma_f32_32x32x16_bf16(ak1, bq[s], st1, 0, 0, 0);    \
    }                                                                             \
    __builtin_amdgcn_s_setprio(0);                                                \
  } while (0)

#define SOFTMAX()                                                                  \
  do {                                                                            \
    _Pragma("unroll") for (int kb = 0; kb < 2; ++kb) {                            \
      float pe[16];                                                               \
      _Pragma("unroll") for (int r = 0; r < 16; ++r)                              \
          pe[r] = __builtin_amdgcn_exp2f(kb ? st1[r] : st0[r]);                   \
      _Pragma("unroll") for (int j = 0; j < 8; ++j) {                             \
        u32 d_;                                                                   \
        asm("v_cvt_pk_bf16_f32 %0, %1, %2"                                        \
            : "=v"(d_)                                                            \
            : "v"(pe[2 * j]), "v"(pe[2 * j + 1]));                                \
        mm[kb * 8 + j] = d_;                                                      \
      }                                                                           \
      asm volatile("v_permlane32_swap_b32 %0, %1"                                 \
                   : "+v"(mm[kb * 8 + 0]), "+v"(mm[kb * 8 + 2]));                 \
      asm volatile("v_permlane32_swap_b32 %0, %1"                                 \
                   : "+v"(mm[kb * 8 + 1]), "+v"(mm[kb * 8 + 3]));                 \
      asm volatile("v_permlane32_swap_b32 %0, %1"                                 \
                   : "+v"(mm[kb * 8 + 4]), "+v"(mm[kb * 8 + 6]));                 \
      asm volatile("v_permlane32_swap_b32 %0, %1"                                 \
                   : "+v"(mm[kb * 8 + 5]), "+v"(mm[kb * 8 + 7]));                 \
    }                                                                             \
  } while (0)

#define PV(Vt_)                                                                    \
  do {                                                                            \
    __builtin_amdgcn_s_setprio(1);                                                \
    _Pragma("unroll") for (int kb = 0; kb < 2; ++kb) {                            \
      _Pragma("unroll") for (int s2 = 0; s2 < 2; ++s2) {                          \
        union { u32 u[4]; bf16x8 v; } pu;                                         \
        pu.u[0] = mm[kb * 8 + s2 * 4 + 0];                                        \
        pu.u[1] = mm[kb * 8 + s2 * 4 + 1];                                        \
        pu.u[2] = mm[kb * 8 + s2 * 4 + 2];                                        \
        pu.u[3] = mm[kb * 8 + s2 * 4 + 3];                                        \
        const bf16x8 pa = pu.v;                                                   \
        acc_l = __builtin_amdgcn_mfma_f32_32x32x16_bf16(pa, ones, acc_l, 0, 0, 0);\
        _Pragma("unroll") for (int db = 0; db < 4; ++db) {                        \
          const int r2 = (db & 1) * 32 + ll;                                      \
          const int c = ((((db >> 1) ^ ((ll >> 3) & 1)) << 3) |                   \
                         ((kb * 4 + s2 * 2 + hi) ^ (ll & 7)));                    \
          const bf16x8 bv = *(const bf16x8*)&(Vt_)[r2 * 128 + c * 8];             \
          acc_o[db] =                                                             \
              __builtin_amdgcn_mfma_f32_32x32x16_bf16(pa, bv, acc_o[db], 0, 0, 0);\
        }                                                                         \
      }                                                                           \
    }                                                                             \
    __builtin_amdgcn_s_setprio(0);                                                \
  } while (0)

  f32x16 acc_o[4] = {};
  f32x16 acc_l = {};
  f32x16 st0, st1;
  u32 mm[16];

  STAGE(0, 0);
  int buf = 0;
  for (int t = 0; t < 15; ++t) {
    STAGE(buf ^ 1, t + 1);
    asm volatile("s_waitcnt vmcnt(8)" ::: "memory");  // tile t's loads landed
    __builtin_amdgcn_s_barrier();
    __builtin_amdgcn_sched_barrier(0);
    QK(Ks[buf]);
    SOFTMAX();
    PV(Vs[buf]);
    __builtin_amdgcn_s_barrier();  // release buf for next iteration's DMA
    buf ^= 1;
  }
  asm volatile("s_waitcnt vmcnt(0)" ::: "memory");
  __builtin_amdgcn_s_barrier();
  __builtin_amdgcn_sched_barrier(0);
  QK(Ks[buf]);
  SOFTMAX();
  PV(Vs[buf]);

#undef STAGE
#undef QK
#undef SOFTMAX
#undef PV

  float inv[16];
  #pragma unroll
  for (int r = 0; r < 16; ++r) inv[r] = __builtin_amdgcn_rcpf(acc_l[r]);
  u16* Ob = attn_out + (size_t)(b * 1024 + wq0) * 1024 + h * 128;
  #pragma unroll
  for (int db = 0; db < 4; ++db)
    #pragma unroll
    for (int r = 0; r < 16; ++r) {
      const int q = (r & 3) + 8 * (r >> 2) + 4 * hi;
      Ob[(size_t)q * 1024 + db * 32 + ll] = f2bf(acc_o[db][r] * inv[r]);
    }
}

extern "C" void kernel_launch(void* const* d_in, const int* in_sizes, int n_in,
                              void* d_out, int out_size, void* d_ws, size_t ws_size,
                              hipStream_t stream) {
  const float* x = (const float*)d_in[0];      // (2,4,1024,512)
  const float* Wqkv = (const float*)d_in[1];   // (512,3072)
  const float* bqkv = (const float*)d_in[2];   // (3072,)
  const float* Wout = (const float*)d_in[3];   // (1024,512)
  const float* bout = (const float*)d_in[4];   // (512,)
  float* out = (float*)d_out;                  // (2,4,1024,512) fp32

  char* ws = (char*)d_ws;
  u16* xb    = (u16*)(ws);                         // 8192*512   bf16 (8.0 MB)
  u16* wqkvt = (u16*)(ws + 8388608);               // 3072*512   bf16 (3.0 MB)
  u16* woutt = (u16*)(ws + 8388608 + 3145728);     // 512*1024   bf16 (1.0 MB)
  u16* qkvb  = (u16*)(ws + 12582912);              // 8192*3072  bf16 (48 MB; V third unused)
  u16* vtb   = (u16*)(ws + 62914560);              // 64*128*1024 bf16 (16 MB)
  u16* aob   = (u16*)(ws + 79691776);              // 8192*1024  bf16 (16 MB)
  float* bq2 = (float*)aob;                        // 3072 f32 (12 KB; consumed pre-attn)

  prep_fused<<<4108, 256, 0, stream>>>(x, xb, bqkv, bq2, Wqkv, wqkvt, Wout, woutt);

  // QKV = x @ W_qkv + b_qkv; Q/K -> qkvb, V -> vtb transposed (fused)
  gemm_qkv_8ph<<<dim3(512), 512, 0, stream>>>(xb, wqkvt, bq2, qkvb, vtb,
                                              8192, 3072, 512);

  attn_fwd<<<dim3(8, 64), 256, 0, stream>>>(qkvb, vtb, aob);

  // out = attn_out @ W_out + b_out  (M=8192, N=512, K=1024), fp32 out
  gemm_bt<128, 64, 32, 0><<<dim3(8, 64), 256, 0, stream>>>(aob, woutt, bout, out,
                                                           8192, 512, 1024);
}